// Round 15
// baseline (4396.103 us; speedup 1.0000x reference)
//
#include <hip/hip_runtime.h>
#include <math.h>

// Problem constants
#define F_DIM 321
#define H_DIM 4200
#define T_DIM 1000
#define NBC   16      // B*C = 8*2
#define KTOP  3
#define PADV  1e-8f

// GEMM tiling. B is NOT staged in LDS: r12-r14 showed the structure is
// LDS-pipe-bound (128 b128/kt-wave x 12cyc = 1536 LDS-cyc vs 4096 VALU-cyc
// per wave, 4 waves share 1 LDS pipe -> 1.5x oversubscribed, 412us floor).
// B comes straight from global (L1-hot: 256B contiguous per 16-lane group,
// 4-way ty broadcast), register-double-buffered across g-phases. LDS holds
// only the A tile (h-major, XOR-swizzled) -> LDS demand 3072 < VALU 4096.
#define BM 128        // h rows per block tile
#define BN 128        // t cols per block tile
#define BK 32
#define LDA 32        // A row stride (words); XOR swizzle on write AND read
#define NHT 33        // ceil(H_DIM / BM)
#define NKT 10        // k-tiles of 32 covering k=0..319 (tail k=320 separate)

typedef float v4f __attribute__((ext_vector_type(4)));

__device__ __forceinline__ void ins3(float v, int i,
                                     float& v0, float& v1, float& v2,
                                     int& i0, int& i1, int& i2) {
  // strict '>' keeps earlier (smaller-h) entries ahead on ties == lax.top_k
  if (v > v0)      { v2 = v1; i2 = i1; v1 = v0; i1 = i0; v0 = v; i0 = i; }
  else if (v > v1) { v2 = v1; i2 = i1; v1 = v;  i1 = i; }
  else if (v > v2) { v2 = v;  i2 = i; }
}

// K1: fused fp32 GEMM (nominee = integral_m @ mag[bc]) + running top-3 over h.
__global__ __launch_bounds__(256)
void hi_k1_gemm_top3(const float* __restrict__ mag,
                     const float* __restrict__ im,
                     float* __restrict__ wv, int* __restrict__ wi,
                     int nsplit) {
  const int tid = threadIdx.x;
  const int tx = tid & 15;
  const int ty = tid >> 4;        // 16 row-groups of 8
  const int th = tid >> 5;        // 0..7 (A staging row-within-round)
  const int kq = tid & 31;        // A staging k word
  const int t0 = blockIdx.x * BN;
  const int bc = blockIdx.y;
  const int sp = blockIdx.z;
  const int ht_begin = (sp * NHT) / nsplit;
  const int ht_end   = ((sp + 1) * NHT) / nsplit;
  const int row0 = ty * 8;
  const int xsw = (ty & 3) << 2;  // A bank swizzle for this thread's rows
  const int wvi = tid >> 6;       // wave index 0..3

  __shared__ __align__(16) float As[2][BM * LDA];  // [h][k^swz] dbuf, 16KB ea

  const float* magbc = mag + (size_t)bc * F_DIM * T_DIM;
  const float* pB = magbc + t0 + tx * 4;   // per-thread B column base

  float ar[16];   // staged A words (global->reg->LDS)

  // issue A global loads for tile (nh0, nk0) into registers (no waiting)
  auto gloadA = [&](int nh0, int nk0) {
#pragma unroll
    for (int l = 0; l < 16; ++l) {
      int gh = nh0 + th + 8 * l;
      gh = (gh < H_DIM) ? gh : (H_DIM - 1);   // clamp: dup row, masked later
      ar[l] = im[(size_t)gh * F_DIM + nk0 + kq];
    }
  };
  // write staged A into LDS buffer (compiler inserts vmcnt waits)
  auto dswriteA = [&](int buf) {
#pragma unroll
    for (int l = 0; l < 16; ++l) {
      int hh = th + 8 * l;                    // (hh>>3)&3 == l&3
      As[buf][hh * LDA + (kq ^ ((l & 3) << 2))] = ar[l];
    }
  };

  float gv0 = -INFINITY, gv1 = -INFINITY, gv2 = -INFINITY;
  int   gi0 = 0, gi1 = 0, gi2 = 0;

  v4f Bc[8], Bn[8];   // B register double-buffer (one g-phase = 4k x 8c)

  // load 8 B fragments for absolute k-base kb (4 consecutive k rows)
  auto loadB = [&](v4f* D, int kb) {
#pragma unroll
    for (int kk = 0; kk < 4; ++kk) {
      D[kk * 2]     = *(const v4f*)(pB + (size_t)(kb + kk) * T_DIM);
      D[kk * 2 + 1] = *(const v4f*)(pB + (size_t)(kb + kk) * T_DIM + 64);
    }
  };

  int cur = 0;
  gloadA(ht_begin * BM, 0);
  dswriteA(0);
  loadB(Bc, 0);        // B for kt=0, g=0 (lands during barrier)
  __syncthreads();

  for (int ht = ht_begin; ht < ht_end; ++ht) {
    const int h0 = ht * BM;
    float acc[8][8];
#pragma unroll
    for (int r = 0; r < 8; ++r)
#pragma unroll
      for (int c = 0; c < 8; ++c) acc[r][c] = 0.f;

    for (int kt = 0; kt < NKT; ++kt) {
      const int k0 = kt * BK;
      // issue next A tile's global loads (this ht's kt+1, or next ht's kt 0)
      bool have_next = true;
      int nh0 = h0, nk0 = (kt + 1) * BK;
      if (kt == NKT - 1) {
        if (ht + 1 < ht_end) { nh0 = h0 + BM; nk0 = 0; }
        else have_next = false;
      }
      if (have_next) gloadA(nh0, nk0);

      // 8 g-phases; B reg-dbuf: load g+1 while FMA-ing g. Entering each kt,
      // Bc holds this kt's g0 (loaded during previous kt's phase 7).
#pragma unroll
      for (int gp = 0; gp < 4; ++gp) {
        const int ge = 2 * gp;        // even phase, uses Bc
        if (ge < 7) loadB(Bn, k0 + (ge + 1) * 4);
#pragma unroll
        for (int r = 0; r < 8; ++r) {
          const v4f Ar = *(const v4f*)(&As[cur][(row0 + r) * LDA + ((ge * 4) ^ xsw)]);
#pragma unroll
          for (int kk = 0; kk < 4; ++kk)
#pragma unroll
            for (int c = 0; c < 4; ++c) {
              acc[r][c]     = fmaf(Ar[kk], Bc[kk * 2][c],     acc[r][c]);
              acc[r][c + 4] = fmaf(Ar[kk], Bc[kk * 2 + 1][c], acc[r][c + 4]);
            }
        }
        const int go = 2 * gp + 1;    // odd phase, uses Bn
        if (go < 7) loadB(Bc, k0 + (go + 1) * 4);
        else if (!(kt == NKT - 1 && ht + 1 >= ht_end))
          loadB(Bc, (kt < NKT - 1) ? (kt + 1) * BK : 0);   // next kt's g0
#pragma unroll
        for (int r = 0; r < 8; ++r) {
          const v4f Ar = *(const v4f*)(&As[cur][(row0 + r) * LDA + ((go * 4) ^ xsw)]);
#pragma unroll
          for (int kk = 0; kk < 4; ++kk)
#pragma unroll
            for (int c = 0; c < 4; ++c) {
              acc[r][c]     = fmaf(Ar[kk], Bn[kk * 2][c],     acc[r][c]);
              acc[r][c + 4] = fmaf(Ar[kk], Bn[kk * 2 + 1][c], acc[r][c + 4]);
            }
        }
      }

      if (have_next) dswriteA(cur ^ 1);
      __syncthreads();
      cur ^= 1;
    }

    // K tail: k = 320 (single column), straight from global (L2-resident)
    {
      float bt[8];
#pragma unroll
      for (int c = 0; c < 8; ++c) {
        int gt = t0 + ((c < 4) ? (tx * 4 + c) : (64 + tx * 4 + c - 4));
        bt[c] = (gt < T_DIM) ? magbc[(size_t)(F_DIM - 1) * T_DIM + gt] : 0.f;
      }
#pragma unroll
      for (int r = 0; r < 8; ++r) {
        int gh = h0 + row0 + r;
        float a = (gh < H_DIM) ? im[(size_t)gh * F_DIM + (F_DIM - 1)] : 0.f;
#pragma unroll
        for (int c = 0; c < 8; ++c) acc[r][c] = fmaf(a, bt[c], acc[r][c]);
      }
    }

    // merge scratch aliases the DEAD dbuf half (cur^1 consumed this ht; next
    // ht's prefetched A sits in [cur]). 4096 words available, 3072 used.
    float* mv = (float*)&As[cur ^ 1][0];      // [4][128][3] floats
    int*   mi = (int*)&As[cur ^ 1][1536];     // [4][128][3] ints

    // per-column top-3 over own 8 rows (h ascending), then merge the 4
    // ty-bands in each wave (shfl_down 16 then 32 keeps ascending-h order)
#pragma unroll
    for (int c = 0; c < 8; ++c) {
      const int col = (c < 4) ? (tx * 4 + c) : (64 + tx * 4 + c - 4);
      float v0 = -INFINITY, v1 = -INFINITY, v2 = -INFINITY;
      int   i0 = 0, i1 = 0, i2 = 0;
#pragma unroll
      for (int r = 0; r < 8; ++r) {
        int gh = h0 + row0 + r;
        float v = (gh < H_DIM) ? acc[r][c] : -INFINITY;
        ins3(v, gh, v0, v1, v2, i0, i1, i2);
      }
#pragma unroll
      for (int s = 0; s < 2; ++s) {
        const int off = 16 << s;
        float ov0 = __shfl_down(v0, off);
        float ov1 = __shfl_down(v1, off);
        float ov2 = __shfl_down(v2, off);
        int   oi0 = __shfl_down(i0, off);
        int   oi1 = __shfl_down(i1, off);
        int   oi2 = __shfl_down(i2, off);
        ins3(ov0, oi0, v0, v1, v2, i0, i1, i2);
        ins3(ov1, oi1, v0, v1, v2, i0, i1, i2);
        ins3(ov2, oi2, v0, v1, v2, i0, i1, i2);
      }
      if ((ty & 3) == 0) {
        mv[(wvi * BN + col) * 3 + 0] = v0;
        mv[(wvi * BN + col) * 3 + 1] = v1;
        mv[(wvi * BN + col) * 3 + 2] = v2;
        mi[(wvi * BN + col) * 3 + 0] = i0;
        mi[(wvi * BN + col) * 3 + 1] = i1;
        mi[(wvi * BN + col) * 3 + 2] = i2;
      }
    }
    __syncthreads();
    // threads 0..127 own one column; merge 4 wave-lists (ascending h bands)
    if (tid < BN) {
#pragma unroll
      for (int w = 0; w < 4; ++w)
#pragma unroll
        for (int j = 0; j < 3; ++j) {
          float v = mv[(w * BN + tid) * 3 + j];
          int   i = mi[(w * BN + tid) * 3 + j];
          ins3(v, i, gv0, gv1, gv2, gi0, gi1, gi2);
        }
    }
    // protect merge reads from next ht's kt=0 dswrite into the same region
    __syncthreads();
  }

  if (tid < BN) {
    int t = t0 + tid;
    if (t < T_DIM) {
      size_t base = ((size_t)(bc * nsplit + sp) * KTOP) * T_DIM + t;
      wv[base]             = gv0;
      wv[base + T_DIM]     = gv1;
      wv[base + 2 * T_DIM] = gv2;
      wi[base]             = gi0;
      wi[base + T_DIM]     = gi1;
      wi[base + 2 * T_DIM] = gi2;
    }
  }
}

// K3: merge the nsplit partial top-3 lists, causal-pool the indices, gather
// harmonic_loc rows, sum over K, threshold, write (B,C,F,T) coalesced.
__global__ __launch_bounds__(256, 4)
void hi_k3_pool_gather(const float* __restrict__ wv, const int* __restrict__ wi,
                       const float* __restrict__ hl, float* __restrict__ out,
                       int nsplit) {
  const int tid = threadIdx.x;
  const int t0 = blockIdx.x * 64;
  const int bc = blockIdx.y;

  __shared__ float pos_lds[66 * KTOP];   // t0-2 .. t0+63
  __shared__ int   rows[64 * KTOP];
  __shared__ float S[64 * 65];           // [t_local][f_chunk] transpose buffer

  if (tid < 66) {
    int t = t0 - 2 + tid;
    float p0 = PADV, p1 = PADV, p2 = PADV;
    if (t >= 0 && t < T_DIM) {
      float v0 = -INFINITY, v1 = -INFINITY, v2 = -INFINITY;
      int i0 = 0, i1 = 0, i2 = 0;
      for (int sp = 0; sp < nsplit; ++sp)        // ascending h ranges
        for (int j = 0; j < KTOP; ++j) {         // descending values
          size_t idx = ((size_t)(bc * nsplit + sp) * KTOP + j) * T_DIM + t;
          ins3(wv[idx], wi[idx], v0, v1, v2, i0, i1, i2);
        }
      p0 = (float)i0; p1 = (float)i1; p2 = (float)i2;
    }
    pos_lds[tid * KTOP + 0] = p0;
    pos_lds[tid * KTOP + 1] = p1;
    pos_lds[tid * KTOP + 2] = p2;
  }
  __syncthreads();
  if (tid < 64) {
#pragma unroll
    for (int k = 0; k < KTOP; ++k) {
      float s = (pos_lds[tid * KTOP + k] + pos_lds[(tid + 1) * KTOP + k])
                + pos_lds[(tid + 2) * KTOP + k];
      rows[tid * KTOP + k] = (int)(s / 3.0f);   // matches ref fp32 /3 + int cast
    }
  }
  __syncthreads();

  const int w = tid >> 6, lane = tid & 63;
  for (int fc = 0; fc < 6; ++fc) {
    const int f0 = fc * 64;
    for (int i = 0; i < 16; ++i) {
      int tl = w * 16 + i;
      int r0 = rows[tl * KTOP + 0];
      int r1 = rows[tl * KTOP + 1];
      int r2 = rows[tl * KTOP + 2];
      int f = f0 + lane;
      float s = 0.f;
      if (f < F_DIM)
        s = (hl[(size_t)r0 * F_DIM + f] + hl[(size_t)r1 * F_DIM + f])
            + hl[(size_t)r2 * F_DIM + f];
      S[tl * 65 + lane] = s;
    }
    __syncthreads();
#pragma unroll
    for (int i = 0; i < 16; ++i) {
      int e = tid + 256 * i;
      int fl = e >> 6, tl = e & 63;
      int f = f0 + fl, t = t0 + tl;
      if (f < F_DIM && t < T_DIM)
        out[((size_t)bc * F_DIM + f) * T_DIM + t] = (S[tl * 65 + fl] > 0.f) ? 1.f : 0.f;
    }
    __syncthreads();
  }
}

extern "C" void kernel_launch(void* const* d_in, const int* in_sizes, int n_in,
                              void* d_out, int out_size, void* d_ws, size_t ws_size,
                              hipStream_t stream) {
  const float* mag = (const float*)d_in[0];   // (8,2,321,1000)
  const float* im  = (const float*)d_in[1];   // (4200,321)
  const float* hl  = (const float*)d_in[2];   // (4200,321)
  float* out = (float*)d_out;                 // (8,2,321,1000)

  // nsplit=8 needs 16*8*3*1000*8B = 3.07 MB of ws; fall back to 4 if tight.
  int nsplit = (ws_size >= (size_t)NBC * 8 * KTOP * T_DIM * 8) ? 8 : 4;
  float* wv = (float*)d_ws;
  int*   wi = (int*)d_ws + (size_t)NBC * nsplit * KTOP * T_DIM;

  dim3 g1((T_DIM + BN - 1) / BN, NBC, nsplit);   // 8 x 16 x 8 = 1024 blocks
  hipLaunchKernelGGL(hi_k1_gemm_top3, g1, dim3(256), 0, stream, mag, im, wv, wi, nsplit);

  dim3 g3((T_DIM + 63) / 64, NBC);               // 16 x 16 = 256 blocks
  hipLaunchKernelGGL(hi_k3_pool_gather, g3, dim3(256), 0, stream, wv, wi, hl, out, nsplit);
}

// Round 16
// 1152.949 us; speedup vs baseline: 3.8129x; 3.8129x over previous
//
#include <hip/hip_runtime.h>
#include <math.h>

// Problem constants
#define F_DIM 321
#define H_DIM 4200
#define T_DIM 1000
#define NBC   16      // B*C = 8*2
#define KTOP  3
#define PADV  1e-8f

// GEMM tiling. ONLY A is staged in LDS (r12-r14: B-in-LDS made the shared
// LDS pipe the limiter at 1.5x oversubscription -> 983us plateau; r15's
// B-from-global was right but the lambda/pointer reg-dbuf spilled to scratch
// at 256 VGPR). B fragments load straight from global inside the phase loop
// (inline, static-indexed, one phase live): L1/L2-hot, 256B contiguous per
// 16-lane group, 4-way ty broadcast. Per-SIMD budget per kt: LDS ~1728 cyc
// < VALU 2048 cyc -> VALU-bound.
#define BM 128        // h rows per block tile
#define BN 128        // t cols per block tile
#define BK 16
#define LDA 16        // A row stride (words); XOR swizzle on write AND read
#define NHT 33        // ceil(H_DIM / BM)
#define NKT 20        // k-tiles of 16 covering k=0..319 (tail k=320 separate)

typedef float v4f __attribute__((ext_vector_type(4)));

__device__ __forceinline__ void ins3(float v, int i,
                                     float& v0, float& v1, float& v2,
                                     int& i0, int& i1, int& i2) {
  // strict '>' keeps earlier (smaller-h) entries ahead on ties == lax.top_k
  if (v > v0)      { v2 = v1; i2 = i1; v1 = v0; i1 = i0; v0 = v; i0 = i; }
  else if (v > v1) { v2 = v1; i2 = i1; v1 = v;  i1 = i; }
  else if (v > v2) { v2 = v;  i2 = i; }
}

// K1: fused fp32 GEMM (nominee = integral_m @ mag[bc]) + running top-3 over h.
// Reg-staged A prefetch pipeline (issue A loads -> compute -> ds_write -> one
// barrier per kt). The first B-use vmcnt wait in phase 0 also drains the A
// prefetch (vmcnt is in-order) -- one combined ~L2-latency stall per kt,
// hidden across the 4 waves/SIMD.
__global__ __launch_bounds__(256)
void hi_k1_gemm_top3(const float* __restrict__ mag,
                     const float* __restrict__ im,
                     float* __restrict__ wv, int* __restrict__ wi,
                     int nsplit) {
  const int tid = threadIdx.x;
  const int tx = tid & 15;
  const int ty = tid >> 4;        // 16 row-groups of 8
  const int t0 = blockIdx.x * BN;
  const int bc = blockIdx.y;
  const int sp = blockIdx.z;
  const int ht_begin = (sp * NHT) / nsplit;
  const int ht_end   = ((sp + 1) * NHT) / nsplit;
  const int row0 = ty * 8;
  const int xsw = (ty & 3) << 2;  // A bank swizzle for this thread's rows
  const int wvi = tid >> 6;       // wave index 0..3

  __shared__ __align__(16) float As[2][BM * LDA];  // [h][k^swz] dbuf, 8KB ea
  __shared__ float mv[4 * BN * KTOP];              // merge scratch (separate)
  __shared__ int   mi[4 * BN * KTOP];

  const float* magbc = mag + (size_t)bc * F_DIM * T_DIM;
  const float* pB = magbc + t0 + tx * 4;   // per-thread B column base

  float ar[8];   // staged A words (global->reg->LDS)

  // issue A global loads for tile (nh0, nk0) into registers (no waiting)
  auto gloadA = [&](int nh0, int nk0) {
#pragma unroll
    for (int l = 0; l < 8; ++l) {
      int gh = nh0 + (tid >> 4) + 16 * l;
      gh = (gh < H_DIM) ? gh : (H_DIM - 1);   // clamp: dup row, masked later
      ar[l] = im[(size_t)gh * F_DIM + nk0 + (tid & 15)];
    }
  };
  // write staged A into LDS buffer (compiler inserts vmcnt waits)
  auto dswriteA = [&](int buf) {
#pragma unroll
    for (int l = 0; l < 8; ++l) {
      int hh = (tid >> 4) + 16 * l;
      As[buf][hh * LDA + ((tid & 15) ^ (((hh >> 3) & 3) << 2))] = ar[l];
    }
  };

  float gv0 = -INFINITY, gv1 = -INFINITY, gv2 = -INFINITY;
  int   gi0 = 0, gi1 = 0, gi2 = 0;

  int cur = 0;
  gloadA(ht_begin * BM, 0);
  dswriteA(0);
  __syncthreads();

  for (int ht = ht_begin; ht < ht_end; ++ht) {
    const int h0 = ht * BM;
    float acc[8][8];
#pragma unroll
    for (int r = 0; r < 8; ++r)
#pragma unroll
      for (int c = 0; c < 8; ++c) acc[r][c] = 0.f;

    for (int kt = 0; kt < NKT; ++kt) {
      const int k0 = kt * BK;
      // 1) issue next A tile's loads (this ht's kt+1, or next ht's kt 0)
      bool have_next = true;
      int nh0 = h0, nk0 = (kt + 1) * BK;
      if (kt == NKT - 1) {
        if (ht + 1 < ht_end) { nh0 = h0 + BM; nk0 = 0; }
        else have_next = false;
      }
      if (have_next) gloadA(nh0, nk0);

      // 2) compute: 4 groups of 4 k; B straight from global (L1/L2-hot)
#pragma unroll 1
      for (int g = 0; g < 4; ++g) {
        v4f Bv[8];
#pragma unroll
        for (int kk = 0; kk < 4; ++kk) {
          const float* pk = pB + (size_t)(k0 + g * 4 + kk) * T_DIM;
          Bv[kk * 2]     = *(const v4f*)(pk);
          Bv[kk * 2 + 1] = *(const v4f*)(pk + 64);
        }
#pragma unroll
        for (int r = 0; r < 8; ++r) {
          const v4f Ar = *(const v4f*)(&As[cur][(row0 + r) * LDA + ((g * 4) ^ xsw)]);
#pragma unroll
          for (int kk = 0; kk < 4; ++kk)
#pragma unroll
            for (int c = 0; c < 4; ++c) {
              acc[r][c]     = fmaf(Ar[kk], Bv[kk * 2][c],     acc[r][c]);
              acc[r][c + 4] = fmaf(Ar[kk], Bv[kk * 2 + 1][c], acc[r][c + 4]);
            }
        }
      }

      // 3) land staged A in the other buffer; 4) one barrier per kt
      if (have_next) dswriteA(cur ^ 1);
      __syncthreads();
      cur ^= 1;
    }

    // K tail: k = 320 (single column), straight from global (L2-resident)
    {
      float bt[8];
#pragma unroll
      for (int c = 0; c < 8; ++c) {
        int gt = t0 + ((c < 4) ? (tx * 4 + c) : (64 + tx * 4 + c - 4));
        bt[c] = (gt < T_DIM) ? magbc[(size_t)(F_DIM - 1) * T_DIM + gt] : 0.f;
      }
#pragma unroll
      for (int r = 0; r < 8; ++r) {
        int gh = h0 + row0 + r;
        float a = (gh < H_DIM) ? im[(size_t)gh * F_DIM + (F_DIM - 1)] : 0.f;
#pragma unroll
        for (int c = 0; c < 8; ++c) acc[r][c] = fmaf(a, bt[c], acc[r][c]);
      }
    }

    // per-column top-3 over own 8 rows (h ascending), then merge the 4
    // ty-bands in each wave (shfl_down 16 then 32 keeps ascending-h order)
#pragma unroll
    for (int c = 0; c < 8; ++c) {
      const int col = (c < 4) ? (tx * 4 + c) : (64 + tx * 4 + c - 4);
      float v0 = -INFINITY, v1 = -INFINITY, v2 = -INFINITY;
      int   i0 = 0, i1 = 0, i2 = 0;
#pragma unroll
      for (int r = 0; r < 8; ++r) {
        int gh = h0 + row0 + r;
        float v = (gh < H_DIM) ? acc[r][c] : -INFINITY;
        ins3(v, gh, v0, v1, v2, i0, i1, i2);
      }
#pragma unroll
      for (int s = 0; s < 2; ++s) {
        const int off = 16 << s;
        float ov0 = __shfl_down(v0, off);
        float ov1 = __shfl_down(v1, off);
        float ov2 = __shfl_down(v2, off);
        int   oi0 = __shfl_down(i0, off);
        int   oi1 = __shfl_down(i1, off);
        int   oi2 = __shfl_down(i2, off);
        ins3(ov0, oi0, v0, v1, v2, i0, i1, i2);
        ins3(ov1, oi1, v0, v1, v2, i0, i1, i2);
        ins3(ov2, oi2, v0, v1, v2, i0, i1, i2);
      }
      if ((ty & 3) == 0) {
        mv[(wvi * BN + col) * 3 + 0] = v0;
        mv[(wvi * BN + col) * 3 + 1] = v1;
        mv[(wvi * BN + col) * 3 + 2] = v2;
        mi[(wvi * BN + col) * 3 + 0] = i0;
        mi[(wvi * BN + col) * 3 + 1] = i1;
        mi[(wvi * BN + col) * 3 + 2] = i2;
      }
    }
    __syncthreads();
    // threads 0..127 own one column; merge 4 wave-lists (ascending h bands)
    if (tid < BN) {
#pragma unroll
      for (int w = 0; w < 4; ++w)
#pragma unroll
        for (int j = 0; j < 3; ++j) {
          float v = mv[(w * BN + tid) * 3 + j];
          int   i = mi[(w * BN + tid) * 3 + j];
          ins3(v, i, gv0, gv1, gv2, gi0, gi1, gi2);
        }
    }
    // mv/mi reuse next ht is separated by that ht's 20 kt barriers -> safe
  }

  if (tid < BN) {
    int t = t0 + tid;
    if (t < T_DIM) {
      size_t base = ((size_t)(bc * nsplit + sp) * KTOP) * T_DIM + t;
      wv[base]             = gv0;
      wv[base + T_DIM]     = gv1;
      wv[base + 2 * T_DIM] = gv2;
      wi[base]             = gi0;
      wi[base + T_DIM]     = gi1;
      wi[base + 2 * T_DIM] = gi2;
    }
  }
}

// K3: merge the nsplit partial top-3 lists, causal-pool the indices, gather
// harmonic_loc rows, sum over K, threshold, write (B,C,F,T) coalesced.
__global__ __launch_bounds__(256, 4)
void hi_k3_pool_gather(const float* __restrict__ wv, const int* __restrict__ wi,
                       const float* __restrict__ hl, float* __restrict__ out,
                       int nsplit) {
  const int tid = threadIdx.x;
  const int t0 = blockIdx.x * 64;
  const int bc = blockIdx.y;

  __shared__ float pos_lds[66 * KTOP];   // t0-2 .. t0+63
  __shared__ int   rows[64 * KTOP];
  __shared__ float S[64 * 65];           // [t_local][f_chunk] transpose buffer

  if (tid < 66) {
    int t = t0 - 2 + tid;
    float p0 = PADV, p1 = PADV, p2 = PADV;
    if (t >= 0 && t < T_DIM) {
      float v0 = -INFINITY, v1 = -INFINITY, v2 = -INFINITY;
      int i0 = 0, i1 = 0, i2 = 0;
      for (int sp = 0; sp < nsplit; ++sp)        // ascending h ranges
        for (int j = 0; j < KTOP; ++j) {         // descending values
          size_t idx = ((size_t)(bc * nsplit + sp) * KTOP + j) * T_DIM + t;
          ins3(wv[idx], wi[idx], v0, v1, v2, i0, i1, i2);
        }
      p0 = (float)i0; p1 = (float)i1; p2 = (float)i2;
    }
    pos_lds[tid * KTOP + 0] = p0;
    pos_lds[tid * KTOP + 1] = p1;
    pos_lds[tid * KTOP + 2] = p2;
  }
  __syncthreads();
  if (tid < 64) {
#pragma unroll
    for (int k = 0; k < KTOP; ++k) {
      float s = (pos_lds[tid * KTOP + k] + pos_lds[(tid + 1) * KTOP + k])
                + pos_lds[(tid + 2) * KTOP + k];
      rows[tid * KTOP + k] = (int)(s / 3.0f);   // matches ref fp32 /3 + int cast
    }
  }
  __syncthreads();

  const int w = tid >> 6, lane = tid & 63;
  for (int fc = 0; fc < 6; ++fc) {
    const int f0 = fc * 64;
    for (int i = 0; i < 16; ++i) {
      int tl = w * 16 + i;
      int r0 = rows[tl * KTOP + 0];
      int r1 = rows[tl * KTOP + 1];
      int r2 = rows[tl * KTOP + 2];
      int f = f0 + lane;
      float s = 0.f;
      if (f < F_DIM)
        s = (hl[(size_t)r0 * F_DIM + f] + hl[(size_t)r1 * F_DIM + f])
            + hl[(size_t)r2 * F_DIM + f];
      S[tl * 65 + lane] = s;
    }
    __syncthreads();
#pragma unroll
    for (int i = 0; i < 16; ++i) {
      int e = tid + 256 * i;
      int fl = e >> 6, tl = e & 63;
      int f = f0 + fl, t = t0 + tl;
      if (f < F_DIM && t < T_DIM)
        out[((size_t)bc * F_DIM + f) * T_DIM + t] = (S[tl * 65 + fl] > 0.f) ? 1.f : 0.f;
    }
    __syncthreads();
  }
}

extern "C" void kernel_launch(void* const* d_in, const int* in_sizes, int n_in,
                              void* d_out, int out_size, void* d_ws, size_t ws_size,
                              hipStream_t stream) {
  const float* mag = (const float*)d_in[0];   // (8,2,321,1000)
  const float* im  = (const float*)d_in[1];   // (4200,321)
  const float* hl  = (const float*)d_in[2];   // (4200,321)
  float* out = (float*)d_out;                 // (8,2,321,1000)

  // nsplit=8 needs 16*8*3*1000*8B = 3.07 MB of ws; fall back to 4 if tight.
  int nsplit = (ws_size >= (size_t)NBC * 8 * KTOP * T_DIM * 8) ? 8 : 4;
  float* wv = (float*)d_ws;
  int*   wi = (int*)d_ws + (size_t)NBC * nsplit * KTOP * T_DIM;

  dim3 g1((T_DIM + BN - 1) / BN, NBC, nsplit);   // 8 x 16 x 8 = 1024 blocks
  hipLaunchKernelGGL(hi_k1_gemm_top3, g1, dim3(256), 0, stream, mag, im, wv, wi, nsplit);

  dim3 g3((T_DIM + 63) / 64, NBC);               // 16 x 16 = 256 blocks
  hipLaunchKernelGGL(hi_k3_pool_gather, g3, dim3(256), 0, stream, wv, wi, hl, out, nsplit);
}

// Round 17
// 1043.639 us; speedup vs baseline: 4.2123x; 1.1047x over previous
//
#include <hip/hip_runtime.h>
#include <math.h>

// Problem constants
#define F_DIM 321
#define H_DIM 4200
#define T_DIM 1000
#define NBC   16      // B*C = 8*2
#define KTOP  3
#define PADV  1e-8f

// GEMM tiling. Staging via __builtin_amdgcn_global_load_lds (m151: +35% vs
// reg-staging at 128^2 tiles; removes ds_write insts + ar[] regs + the
// pre-barrier register drain). A: width=4, SOURCE pre-swizzled (m173) so the
// LDS image equals r12's write-swizzled layout -> compute side unchanged.
// B: width=16 (t0*4=512B aligned, row stride 4000B = 16B-aligned).
#define BM 128        // h rows per block tile
#define BN 128        // t cols per block tile
#define BK 16
#define LDA 16        // A row stride (words); XOR-swizzled k-groups
#define LDB 128       // B row stride (words)
#define NHT 33        // ceil(H_DIM / BM)
#define NKT 20        // k-tiles of 16 covering k=0..319 (tail k=320 separate)

typedef float v4f __attribute__((ext_vector_type(4)));
typedef __attribute__((address_space(3))) uint32_t lds_u32;
typedef const __attribute__((address_space(1))) uint32_t glb_u32;

__device__ __forceinline__ void ins3(float v, int i,
                                     float& v0, float& v1, float& v2,
                                     int& i0, int& i1, int& i2) {
  // strict '>' keeps earlier (smaller-h) entries ahead on ties == lax.top_k
  if (v > v0)      { v2 = v1; i2 = i1; v1 = v0; i1 = i0; v0 = v; i0 = i; }
  else if (v > v1) { v2 = v1; i2 = i1; v1 = v;  i1 = i; }
  else if (v > v2) { v2 = v;  i2 = i; }
}

// K1: fused fp32 GEMM (nominee = integral_m @ mag[bc]) + running top-3 over h.
// T3-minimum schedule: issue next tile's global_load_lds BEFORE compute, one
// barrier per kt (its vmcnt drain is covered by the 2048-cyc compute phase).
__global__ __launch_bounds__(256)
void hi_k1_gemm_top3(const float* __restrict__ mag,
                     const float* __restrict__ im,
                     float* __restrict__ wv, int* __restrict__ wi,
                     int nsplit) {
  const int tid = threadIdx.x;
  const int tx = tid & 15;
  const int ty = tid >> 4;        // 16 row-groups of 8
  const int wv_ = tid >> 6;       // wave index 0..3
  const int lam = tid & 63;       // lane within wave
  const int t0 = blockIdx.x * BN;
  const int bc = blockIdx.y;
  const int sp = blockIdx.z;
  const int ht_begin = (sp * NHT) / nsplit;
  const int ht_end   = ((sp + 1) * NHT) / nsplit;
  const int row0 = ty * 8;
  const int xsw = (ty & 3) << 2;  // A read swizzle (== write-side key)

  __shared__ __align__(16) float As[2][BM * LDA];  // [h][k^swz] dbuf, 8KB ea
  __shared__ __align__(16) float Bs[2][BK * LDB];  // [k][t] dbuf, 8KB ea
  __shared__ float mv[4 * BN * KTOP];              // merge scratch (separate)
  __shared__ int   mi[4 * BN * KTOP];

  const float* magbc = mag + (size_t)bc * F_DIM * T_DIM;

  // stage A tile (nh0, nk0) into As[buf] via global_load_lds width=4.
  // inst i covers 4 rows (16 lanes/row, one dword each). LDS dest is linear
  // (wave-uniform base + lane*4); the XOR swizzle is applied to the SOURCE
  // k-index (m173): As[row][j] = im[gh][nk0 + (j ^ key(row))], identical to
  // the r12-r16 write-side layout.
  auto stageA = [&](int buf, int nh0, int nk0) {
#pragma unroll
    for (int i = 0; i < 8; ++i) {
      int row = wv_ * 32 + i * 4 + (lam >> 4);
      int gh = nh0 + row;
      gh = (gh < H_DIM) ? gh : (H_DIM - 1);   // clamp: dup row, masked later
      int key = ((row >> 3) & 3) << 2;
      const float* src = im + (size_t)gh * F_DIM + nk0 + ((lam & 15) ^ key);
      __builtin_amdgcn_global_load_lds(
          (glb_u32*)src,
          (lds_u32*)&As[buf][(wv_ * 32 + i * 4) * LDA], 4, 0, 0);
    }
  };
  // stage B tile rows nk0..nk0+15 into Bs[buf] via width=16 (2 rows/inst).
  auto stageB = [&](int buf, int nk0) {
#pragma unroll
    for (int i = 0; i < 2; ++i) {
      int kr = wv_ * 4 + i * 2 + (lam >> 5);
      const float* src = magbc + (size_t)(nk0 + kr) * T_DIM + t0 + (lam & 31) * 4;
      __builtin_amdgcn_global_load_lds(
          (glb_u32*)src,
          (lds_u32*)&Bs[buf][(wv_ * 4 + i * 2) * LDB], 16, 0, 0);
    }
  };

  float gv0 = -INFINITY, gv1 = -INFINITY, gv2 = -INFINITY;
  int   gi0 = 0, gi1 = 0, gi2 = 0;

  int cur = 0;
  stageA(0, ht_begin * BM, 0);
  stageB(0, 0);
  __syncthreads();   // drains vmcnt -> tile 0 landed

  for (int ht = ht_begin; ht < ht_end; ++ht) {
    const int h0 = ht * BM;
    float acc[8][8];
#pragma unroll
    for (int r = 0; r < 8; ++r)
#pragma unroll
      for (int c = 0; c < 8; ++c) acc[r][c] = 0.f;

    for (int kt = 0; kt < NKT; ++kt) {
      // 1) issue next tile's async stages (in flight across the compute)
      bool have_next = true;
      int nh0 = h0, nk0 = (kt + 1) * BK;
      if (kt == NKT - 1) {
        if (ht + 1 < ht_end) { nh0 = h0 + BM; nk0 = 0; }
        else have_next = false;
      }
      if (have_next) { stageA(cur ^ 1, nh0, nk0); stageB(cur ^ 1, nk0); }

      // 2) compute current buffer: 4 groups of 4 k
#pragma unroll 1
      for (int g = 0; g < 4; ++g) {
        v4f Bv[8];
#pragma unroll
        for (int kk = 0; kk < 4; ++kk) {
          Bv[kk * 2]     = *(const v4f*)(&Bs[cur][(g * 4 + kk) * LDB + tx * 4]);
          Bv[kk * 2 + 1] = *(const v4f*)(&Bs[cur][(g * 4 + kk) * LDB + 64 + tx * 4]);
        }
#pragma unroll
        for (int r = 0; r < 8; ++r) {
          const v4f Ar = *(const v4f*)(&As[cur][(row0 + r) * LDA + ((g * 4) ^ xsw)]);
#pragma unroll
          for (int kk = 0; kk < 4; ++kk)
#pragma unroll
            for (int c = 0; c < 4; ++c) {
              acc[r][c]     = fmaf(Ar[kk], Bv[kk * 2][c],     acc[r][c]);
              acc[r][c + 4] = fmaf(Ar[kk], Bv[kk * 2 + 1][c], acc[r][c + 4]);
            }
        }
      }

      // 3) one barrier per kt (emits vmcnt drain -> staged tile landed)
      __syncthreads();
      cur ^= 1;
    }

    // K tail: k = 320 (single column), straight from global (L2-resident)
    {
      float bt[8];
#pragma unroll
      for (int c = 0; c < 8; ++c) {
        int gt = t0 + ((c < 4) ? (tx * 4 + c) : (64 + tx * 4 + c - 4));
        bt[c] = (gt < T_DIM) ? magbc[(size_t)(F_DIM - 1) * T_DIM + gt] : 0.f;
      }
#pragma unroll
      for (int r = 0; r < 8; ++r) {
        int gh = h0 + row0 + r;
        float a = (gh < H_DIM) ? im[(size_t)gh * F_DIM + (F_DIM - 1)] : 0.f;
#pragma unroll
        for (int c = 0; c < 8; ++c) acc[r][c] = fmaf(a, bt[c], acc[r][c]);
      }
    }

    // per-column top-3 over own 8 rows (h ascending), then merge the 4
    // ty-bands in each wave (shfl_down 16 then 32 keeps ascending-h order)
#pragma unroll
    for (int c = 0; c < 8; ++c) {
      const int col = (c < 4) ? (tx * 4 + c) : (64 + tx * 4 + c - 4);
      float v0 = -INFINITY, v1 = -INFINITY, v2 = -INFINITY;
      int   i0 = 0, i1 = 0, i2 = 0;
#pragma unroll
      for (int r = 0; r < 8; ++r) {
        int gh = h0 + row0 + r;
        float v = (gh < H_DIM) ? acc[r][c] : -INFINITY;
        ins3(v, gh, v0, v1, v2, i0, i1, i2);
      }
#pragma unroll
      for (int s = 0; s < 2; ++s) {
        const int off = 16 << s;
        float ov0 = __shfl_down(v0, off);
        float ov1 = __shfl_down(v1, off);
        float ov2 = __shfl_down(v2, off);
        int   oi0 = __shfl_down(i0, off);
        int   oi1 = __shfl_down(i1, off);
        int   oi2 = __shfl_down(i2, off);
        ins3(ov0, oi0, v0, v1, v2, i0, i1, i2);
        ins3(ov1, oi1, v0, v1, v2, i0, i1, i2);
        ins3(ov2, oi2, v0, v1, v2, i0, i1, i2);
      }
      if ((ty & 3) == 0) {
        mv[(wv_ * BN + col) * 3 + 0] = v0;
        mv[(wv_ * BN + col) * 3 + 1] = v1;
        mv[(wv_ * BN + col) * 3 + 2] = v2;
        mi[(wv_ * BN + col) * 3 + 0] = i0;
        mi[(wv_ * BN + col) * 3 + 1] = i1;
        mi[(wv_ * BN + col) * 3 + 2] = i2;
      }
    }
    __syncthreads();
    // threads 0..127 own one column; merge 4 wave-lists (ascending h bands)
    if (tid < BN) {
#pragma unroll
      for (int w = 0; w < 4; ++w)
#pragma unroll
        for (int j = 0; j < 3; ++j) {
          float v = mv[(w * BN + tid) * 3 + j];
          int   i = mi[(w * BN + tid) * 3 + j];
          ins3(v, i, gv0, gv1, gv2, gi0, gi1, gi2);
        }
    }
    // mv/mi reuse next ht is separated by that ht's 20 kt barriers -> safe
  }

  if (tid < BN) {
    int t = t0 + tid;
    if (t < T_DIM) {
      size_t base = ((size_t)(bc * nsplit + sp) * KTOP) * T_DIM + t;
      wv[base]             = gv0;
      wv[base + T_DIM]     = gv1;
      wv[base + 2 * T_DIM] = gv2;
      wi[base]             = gi0;
      wi[base + T_DIM]     = gi1;
      wi[base + 2 * T_DIM] = gi2;
    }
  }
}

// K3: merge the nsplit partial top-3 lists, causal-pool the indices, gather
// harmonic_loc rows, sum over K, threshold, write (B,C,F,T) coalesced.
__global__ __launch_bounds__(256, 4)
void hi_k3_pool_gather(const float* __restrict__ wv, const int* __restrict__ wi,
                       const float* __restrict__ hl, float* __restrict__ out,
                       int nsplit) {
  const int tid = threadIdx.x;
  const int t0 = blockIdx.x * 64;
  const int bc = blockIdx.y;

  __shared__ float pos_lds[66 * KTOP];   // t0-2 .. t0+63
  __shared__ int   rows[64 * KTOP];
  __shared__ float S[64 * 65];           // [t_local][f_chunk] transpose buffer

  if (tid < 66) {
    int t = t0 - 2 + tid;
    float p0 = PADV, p1 = PADV, p2 = PADV;
    if (t >= 0 && t < T_DIM) {
      float v0 = -INFINITY, v1 = -INFINITY, v2 = -INFINITY;
      int i0 = 0, i1 = 0, i2 = 0;
      for (int sp = 0; sp < nsplit; ++sp)        // ascending h ranges
        for (int j = 0; j < KTOP; ++j) {         // descending values
          size_t idx = ((size_t)(bc * nsplit + sp) * KTOP + j) * T_DIM + t;
          ins3(wv[idx], wi[idx], v0, v1, v2, i0, i1, i2);
        }
      p0 = (float)i0; p1 = (float)i1; p2 = (float)i2;
    }
    pos_lds[tid * KTOP + 0] = p0;
    pos_lds[tid * KTOP + 1] = p1;
    pos_lds[tid * KTOP + 2] = p2;
  }
  __syncthreads();
  if (tid < 64) {
#pragma unroll
    for (int k = 0; k < KTOP; ++k) {
      float s = (pos_lds[tid * KTOP + k] + pos_lds[(tid + 1) * KTOP + k])
                + pos_lds[(tid + 2) * KTOP + k];
      rows[tid * KTOP + k] = (int)(s / 3.0f);   // matches ref fp32 /3 + int cast
    }
  }
  __syncthreads();

  const int w = tid >> 6, lane = tid & 63;
  for (int fc = 0; fc < 6; ++fc) {
    const int f0 = fc * 64;
    for (int i = 0; i < 16; ++i) {
      int tl = w * 16 + i;
      int r0 = rows[tl * KTOP + 0];
      int r1 = rows[tl * KTOP + 1];
      int r2 = rows[tl * KTOP + 2];
      int f = f0 + lane;
      float s = 0.f;
      if (f < F_DIM)
        s = (hl[(size_t)r0 * F_DIM + f] + hl[(size_t)r1 * F_DIM + f])
            + hl[(size_t)r2 * F_DIM + f];
      S[tl * 65 + lane] = s;
    }
    __syncthreads();
#pragma unroll
    for (int i = 0; i < 16; ++i) {
      int e = tid + 256 * i;
      int fl = e >> 6, tl = e & 63;
      int f = f0 + fl, t = t0 + tl;
      if (f < F_DIM && t < T_DIM)
        out[((size_t)bc * F_DIM + f) * T_DIM + t] = (S[tl * 65 + fl] > 0.f) ? 1.f : 0.f;
    }
    __syncthreads();
  }
}

extern "C" void kernel_launch(void* const* d_in, const int* in_sizes, int n_in,
                              void* d_out, int out_size, void* d_ws, size_t ws_size,
                              hipStream_t stream) {
  const float* mag = (const float*)d_in[0];   // (8,2,321,1000)
  const float* im  = (const float*)d_in[1];   // (4200,321)
  const float* hl  = (const float*)d_in[2];   // (4200,321)
  float* out = (float*)d_out;                 // (8,2,321,1000)

  // nsplit=8 needs 16*8*3*1000*8B = 3.07 MB of ws; fall back to 4 if tight.
  int nsplit = (ws_size >= (size_t)NBC * 8 * KTOP * T_DIM * 8) ? 8 : 4;
  float* wv = (float*)d_ws;
  int*   wi = (int*)d_ws + (size_t)NBC * nsplit * KTOP * T_DIM;

  dim3 g1((T_DIM + BN - 1) / BN, NBC, nsplit);   // 8 x 16 x 8 = 1024 blocks
  hipLaunchKernelGGL(hi_k1_gemm_top3, g1, dim3(256), 0, stream, mag, im, wv, wi, nsplit);

  dim3 g3((T_DIM + 63) / 64, NBC);               // 16 x 16 = 256 blocks
  hipLaunchKernelGGL(hi_k3_pool_gather, g3, dim3(256), 0, stream, wv, wi, hl, out, nsplit);
}

// Round 18
// 1025.558 us; speedup vs baseline: 4.2865x; 1.0176x over previous
//
#include <hip/hip_runtime.h>
#include <math.h>

// Problem constants
#define F_DIM 321
#define H_DIM 4200
#define T_DIM 1000
#define NBC   16      // B*C = 8*2
#define KTOP  3
#define PADV  1e-8f

// GEMM tiling. Staging via global_load_lds (r17-verified). NEW in r18:
// counted-vmcnt pipeline (T4, m218 +38-73%): raw s_barrier + s_waitcnt
// vmcnt(10) instead of __syncthreads' vmcnt(0) drain -> the next-next tile's
// loads stay in flight across barriers. m233: the 2-phase drain structure
// caps compute share at ~28%; our r12-r17 plateau (983-1153us, VALUBusy 37%)
// matches exactly.
#define BM 128        // h rows per block tile
#define BN 128        // t cols per block tile
#define BK 16
#define LDA 16        // A row stride (words); XOR-swizzled k-groups
#define LDB 128       // B row stride (words)
#define NHT 33        // ceil(H_DIM / BM)
#define NKT 20        // k-tiles of 16 covering k=0..319 (tail k=320 separate)

typedef float v4f __attribute__((ext_vector_type(4)));
typedef __attribute__((address_space(3))) uint32_t lds_u32;
typedef const __attribute__((address_space(1))) uint32_t glb_u32;

__device__ __forceinline__ void ins3(float v, int i,
                                     float& v0, float& v1, float& v2,
                                     int& i0, int& i1, int& i2) {
  // strict '>' keeps earlier (smaller-h) entries ahead on ties == lax.top_k
  if (v > v0)      { v2 = v1; i2 = i1; v1 = v0; i1 = i0; v0 = v; i0 = i; }
  else if (v > v1) { v2 = v1; i2 = i1; v1 = v;  i1 = i; }
  else if (v > v2) { v2 = v;  i2 = i; }
}

// K1: fused fp32 GEMM (nominee = integral_m @ mag[bc]) + running top-3 over h.
// Counted-vmcnt double-buffer pipeline, 2 tiles in flight:
//   compute(cur) ; s_barrier ; stage(cur, i+2) ; vmcnt(10) [i+1 landed,
//   i+2 still flying] ; s_barrier ; cur^=1
// vmcnt counting is exact inside the loop: only the 10 stage intrinsics/wave
// issue vmem; per-ht merge uses __syncthreads (full drain, once per 20 kt,
// re-zeroing the count).
__global__ __launch_bounds__(256)
void hi_k1_gemm_top3(const float* __restrict__ mag,
                     const float* __restrict__ im,
                     float* __restrict__ wv, int* __restrict__ wi,
                     int nsplit) {
  const int tid = threadIdx.x;
  const int tx = tid & 15;
  const int ty = tid >> 4;        // 16 row-groups of 8
  const int wv_ = tid >> 6;       // wave index 0..3
  const int lam = tid & 63;       // lane within wave
  const int t0 = blockIdx.x * BN;
  const int bc = blockIdx.y;
  const int sp = blockIdx.z;
  const int ht_begin = (sp * NHT) / nsplit;
  const int ht_end   = ((sp + 1) * NHT) / nsplit;
  const int nht = ht_end - ht_begin;
  const int NT = nht * NKT;       // total pipeline tiles for this block
  const int row0 = ty * 8;
  const int xsw = (ty & 3) << 2;  // A read swizzle (== source-side key)

  __shared__ __align__(16) float As[2][BM * LDA];  // [h][k^swz] dbuf, 8KB ea
  __shared__ __align__(16) float Bs[2][BK * LDB];  // [k][t] dbuf, 8KB ea
  __shared__ float mv[4 * BN * KTOP];              // merge scratch (separate)
  __shared__ int   mi[4 * BN * KTOP];

  const float* magbc = mag + (size_t)bc * F_DIM * T_DIM;

  // stage A tile (nh0, nk0) into As[buf]: 8 x global_load_lds width=4.
  // LDS dest is linear (wave-uniform base + lane*4); XOR swizzle applied to
  // the SOURCE k-index (m173) -> LDS image identical to r12's layout.
  auto stageA = [&](int buf, int nh0, int nk0) {
#pragma unroll
    for (int i = 0; i < 8; ++i) {
      int row = wv_ * 32 + i * 4 + (lam >> 4);
      int gh = nh0 + row;
      gh = (gh < H_DIM) ? gh : (H_DIM - 1);   // clamp: dup row, masked later
      int key = ((row >> 3) & 3) << 2;
      const float* src = im + (size_t)gh * F_DIM + nk0 + ((lam & 15) ^ key);
      __builtin_amdgcn_global_load_lds(
          (glb_u32*)src,
          (lds_u32*)&As[buf][(wv_ * 32 + i * 4) * LDA], 4, 0, 0);
    }
  };
  // stage B tile rows nk0..nk0+15 into Bs[buf]: 2 x width=16 (2 rows/inst).
  auto stageB = [&](int buf, int nk0) {
#pragma unroll
    for (int i = 0; i < 2; ++i) {
      int kr = wv_ * 4 + i * 2 + (lam >> 5);
      const float* src = magbc + (size_t)(nk0 + kr) * T_DIM + t0 + (lam & 31) * 4;
      __builtin_amdgcn_global_load_lds(
          (glb_u32*)src,
          (lds_u32*)&Bs[buf][(wv_ * 4 + i * 2) * LDB], 16, 0, 0);
    }
  };
  auto nh0_of = [&](int i) { return (ht_begin + i / NKT) * BM; };
  auto nk0_of = [&](int i) { return (i % NKT) * BK; };

  float gv0 = -INFINITY, gv1 = -INFINITY, gv2 = -INFINITY;
  int   gi0 = 0, gi1 = 0, gi2 = 0;

  // prologue: 2 tiles in flight, wait for tile 0 only (NT >= 80 always)
  stageA(0, nh0_of(0), nk0_of(0)); stageB(0, nk0_of(0));
  stageA(1, nh0_of(1), nk0_of(1)); stageB(1, nk0_of(1));
  asm volatile("s_waitcnt vmcnt(10)" ::: "memory");
  __builtin_amdgcn_s_barrier();
  __builtin_amdgcn_sched_barrier(0);

  int cur = 0;
  for (int ht = 0; ht < nht; ++ht) {
    const int h0 = (ht_begin + ht) * BM;
    float acc[8][8];
#pragma unroll
    for (int r = 0; r < 8; ++r)
#pragma unroll
      for (int c = 0; c < 8; ++c) acc[r][c] = 0.f;

    for (int kt = 0; kt < NKT; ++kt) {
      const int i = ht * NKT + kt;

      // compute current buffer: 4 groups of 4 k
#pragma unroll 1
      for (int g = 0; g < 4; ++g) {
        v4f Bv[8];
#pragma unroll
        for (int kk = 0; kk < 4; ++kk) {
          Bv[kk * 2]     = *(const v4f*)(&Bs[cur][(g * 4 + kk) * LDB + tx * 4]);
          Bv[kk * 2 + 1] = *(const v4f*)(&Bs[cur][(g * 4 + kk) * LDB + 64 + tx * 4]);
        }
#pragma unroll
        for (int r = 0; r < 8; ++r) {
          const v4f Ar = *(const v4f*)(&As[cur][(row0 + r) * LDA + ((g * 4) ^ xsw)]);
#pragma unroll
          for (int kk = 0; kk < 4; ++kk)
#pragma unroll
            for (int c = 0; c < 4; ++c) {
              acc[r][c]     = fmaf(Ar[kk], Bv[kk * 2][c],     acc[r][c]);
              acc[r][c + 4] = fmaf(Ar[kk], Bv[kk * 2 + 1][c], acc[r][c + 4]);
            }
        }
      }

      // barrier 1: all waves done reading buf[cur]
      asm volatile("" ::: "memory");
      __builtin_amdgcn_s_barrier();
      __builtin_amdgcn_sched_barrier(0);   // stage must not hoist above

      if (i + 2 < NT) {
        stageA(cur, nh0_of(i + 2), nk0_of(i + 2));
        stageB(cur, nk0_of(i + 2));
        // wait tile i+1 landed (its 10 are the oldest; i+2's 10 stay out)
        asm volatile("s_waitcnt vmcnt(10)" ::: "memory");
      } else {
        asm volatile("s_waitcnt vmcnt(0)" ::: "memory");
      }
      // barrier 2: every wave's slice of tile i+1 is in LDS
      asm volatile("" ::: "memory");
      __builtin_amdgcn_s_barrier();
      __builtin_amdgcn_sched_barrier(0);   // next compute must not hoist
      cur ^= 1;
    }

    // K tail: k = 320 (single column), straight from global (L2-resident)
    {
      float bt[8];
#pragma unroll
      for (int c = 0; c < 8; ++c) {
        int gt = t0 + ((c < 4) ? (tx * 4 + c) : (64 + tx * 4 + c - 4));
        bt[c] = (gt < T_DIM) ? magbc[(size_t)(F_DIM - 1) * T_DIM + gt] : 0.f;
      }
#pragma unroll
      for (int r = 0; r < 8; ++r) {
        int gh = h0 + row0 + r;
        float a = (gh < H_DIM) ? im[(size_t)gh * F_DIM + (F_DIM - 1)] : 0.f;
#pragma unroll
        for (int c = 0; c < 8; ++c) acc[r][c] = fmaf(a, bt[c], acc[r][c]);
      }
    }

    // per-column top-3 over own 8 rows (h ascending), then merge the 4
    // ty-bands in each wave (shfl_down 16 then 32 keeps ascending-h order).
    // __syncthreads here drains vmcnt to 0 (once per ht) and re-zeros the
    // manual count; in-flight tiles simply land early.
#pragma unroll
    for (int c = 0; c < 8; ++c) {
      const int col = (c < 4) ? (tx * 4 + c) : (64 + tx * 4 + c - 4);
      float v0 = -INFINITY, v1 = -INFINITY, v2 = -INFINITY;
      int   i0 = 0, i1 = 0, i2 = 0;
#pragma unroll
      for (int r = 0; r < 8; ++r) {
        int gh = h0 + row0 + r;
        float v = (gh < H_DIM) ? acc[r][c] : -INFINITY;
        ins3(v, gh, v0, v1, v2, i0, i1, i2);
      }
#pragma unroll
      for (int s = 0; s < 2; ++s) {
        const int off = 16 << s;
        float ov0 = __shfl_down(v0, off);
        float ov1 = __shfl_down(v1, off);
        float ov2 = __shfl_down(v2, off);
        int   oi0 = __shfl_down(i0, off);
        int   oi1 = __shfl_down(i1, off);
        int   oi2 = __shfl_down(i2, off);
        ins3(ov0, oi0, v0, v1, v2, i0, i1, i2);
        ins3(ov1, oi1, v0, v1, v2, i0, i1, i2);
        ins3(ov2, oi2, v0, v1, v2, i0, i1, i2);
      }
      if ((ty & 3) == 0) {
        mv[(wv_ * BN + col) * 3 + 0] = v0;
        mv[(wv_ * BN + col) * 3 + 1] = v1;
        mv[(wv_ * BN + col) * 3 + 2] = v2;
        mi[(wv_ * BN + col) * 3 + 0] = i0;
        mi[(wv_ * BN + col) * 3 + 1] = i1;
        mi[(wv_ * BN + col) * 3 + 2] = i2;
      }
    }
    __syncthreads();
    // threads 0..127 own one column; merge 4 wave-lists (ascending h bands)
    if (tid < BN) {
#pragma unroll
      for (int w = 0; w < 4; ++w)
#pragma unroll
        for (int j = 0; j < 3; ++j) {
          float v = mv[(w * BN + tid) * 3 + j];
          int   i = mi[(w * BN + tid) * 3 + j];
          ins3(v, i, gv0, gv1, gv2, gi0, gi1, gi2);
        }
    }
    __syncthreads();   // mv/mi reads done before next ht reuses them
  }

  if (tid < BN) {
    int t = t0 + tid;
    if (t < T_DIM) {
      size_t base = ((size_t)(bc * nsplit + sp) * KTOP) * T_DIM + t;
      wv[base]             = gv0;
      wv[base + T_DIM]     = gv1;
      wv[base + 2 * T_DIM] = gv2;
      wi[base]             = gi0;
      wi[base + T_DIM]     = gi1;
      wi[base + 2 * T_DIM] = gi2;
    }
  }
}

// K3: merge the nsplit partial top-3 lists, causal-pool the indices, gather
// harmonic_loc rows, sum over K, threshold, write (B,C,F,T) coalesced.
__global__ __launch_bounds__(256, 4)
void hi_k3_pool_gather(const float* __restrict__ wv, const int* __restrict__ wi,
                       const float* __restrict__ hl, float* __restrict__ out,
                       int nsplit) {
  const int tid = threadIdx.x;
  const int t0 = blockIdx.x * 64;
  const int bc = blockIdx.y;

  __shared__ float pos_lds[66 * KTOP];   // t0-2 .. t0+63
  __shared__ int   rows[64 * KTOP];
  __shared__ float S[64 * 65];           // [t_local][f_chunk] transpose buffer

  if (tid < 66) {
    int t = t0 - 2 + tid;
    float p0 = PADV, p1 = PADV, p2 = PADV;
    if (t >= 0 && t < T_DIM) {
      float v0 = -INFINITY, v1 = -INFINITY, v2 = -INFINITY;
      int i0 = 0, i1 = 0, i2 = 0;
      for (int sp = 0; sp < nsplit; ++sp)        // ascending h ranges
        for (int j = 0; j < KTOP; ++j) {         // descending values
          size_t idx = ((size_t)(bc * nsplit + sp) * KTOP + j) * T_DIM + t;
          ins3(wv[idx], wi[idx], v0, v1, v2, i0, i1, i2);
        }
      p0 = (float)i0; p1 = (float)i1; p2 = (float)i2;
    }
    pos_lds[tid * KTOP + 0] = p0;
    pos_lds[tid * KTOP + 1] = p1;
    pos_lds[tid * KTOP + 2] = p2;
  }
  __syncthreads();
  if (tid < 64) {
#pragma unroll
    for (int k = 0; k < KTOP; ++k) {
      float s = (pos_lds[tid * KTOP + k] + pos_lds[(tid + 1) * KTOP + k])
                + pos_lds[(tid + 2) * KTOP + k];
      rows[tid * KTOP + k] = (int)(s / 3.0f);   // matches ref fp32 /3 + int cast
    }
  }
  __syncthreads();

  const int w = tid >> 6, lane = tid & 63;
  for (int fc = 0; fc < 6; ++fc) {
    const int f0 = fc * 64;
    for (int i = 0; i < 16; ++i) {
      int tl = w * 16 + i;
      int r0 = rows[tl * KTOP + 0];
      int r1 = rows[tl * KTOP + 1];
      int r2 = rows[tl * KTOP + 2];
      int f = f0 + lane;
      float s = 0.f;
      if (f < F_DIM)
        s = (hl[(size_t)r0 * F_DIM + f] + hl[(size_t)r1 * F_DIM + f])
            + hl[(size_t)r2 * F_DIM + f];
      S[tl * 65 + lane] = s;
    }
    __syncthreads();
#pragma unroll
    for (int i = 0; i < 16; ++i) {
      int e = tid + 256 * i;
      int fl = e >> 6, tl = e & 63;
      int f = f0 + fl, t = t0 + tl;
      if (f < F_DIM && t < T_DIM)
        out[((size_t)bc * F_DIM + f) * T_DIM + t] = (S[tl * 65 + fl] > 0.f) ? 1.f : 0.f;
    }
    __syncthreads();
  }
}

extern "C" void kernel_launch(void* const* d_in, const int* in_sizes, int n_in,
                              void* d_out, int out_size, void* d_ws, size_t ws_size,
                              hipStream_t stream) {
  const float* mag = (const float*)d_in[0];   // (8,2,321,1000)
  const float* im  = (const float*)d_in[1];   // (4200,321)
  const float* hl  = (const float*)d_in[2];   // (4200,321)
  float* out = (float*)d_out;                 // (8,2,321,1000)

  // nsplit=8 needs 16*8*3*1000*8B = 3.07 MB of ws; fall back to 4 if tight.
  int nsplit = (ws_size >= (size_t)NBC * 8 * KTOP * T_DIM * 8) ? 8 : 4;
  float* wv = (float*)d_ws;
  int*   wi = (int*)d_ws + (size_t)NBC * nsplit * KTOP * T_DIM;

  dim3 g1((T_DIM + BN - 1) / BN, NBC, nsplit);   // 8 x 16 x 8 = 1024 blocks
  hipLaunchKernelGGL(hi_k1_gemm_top3, g1, dim3(256), 0, stream, mag, im, wv, wi, nsplit);

  dim3 g3((T_DIM + 63) / 64, NBC);               // 16 x 16 = 256 blocks
  hipLaunchKernelGGL(hi_k3_pool_gather, g3, dim3(256), 0, stream, wv, wi, hl, out, nsplit);
}

// Round 19
// 960.334 us; speedup vs baseline: 4.5777x; 1.0679x over previous
//
#include <hip/hip_runtime.h>
#include <math.h>

// Problem constants
#define F_DIM 321
#define H_DIM 4200
#define T_DIM 1000
#define NBC   16      // B*C = 8*2
#define KTOP  3
#define PADV  1e-8f

// NEW decomposition (r19): wave-uniform rows. Block = 4 waves; wave w owns
// rows h0+8w..h0+8w+7 (uniform across lanes) x 256 cols (lane owns 4).
// A elements are wave-uniform -> readfirstlane-forced uniform addresses ->
// scalar loads (SMEM pipe + scalar cache), consumed as the SGPR operand of
// v_fmac_f32. Only B goes through LDS: 16 b128/wave/kt -> LDS:VALU demand
// 0.75 (was 1.5x oversubscribed in ALL r12-r18 variants -> 983-1153us
// plateau at 38% dual-pipe utilization). acc = 32 regs -> high occupancy.
#define BM 32         // h rows per block tile (4 waves x 8)
#define BN 256        // t cols per block tile (64 lanes x 4)
#define BK 16
#define NRT 132       // ceil(H_DIM / BM)
#define NKT 20        // k-tiles of 16 covering k=0..319 (tail k=320 separate)
#define NTT 4         // ceil(T_DIM / BN)

typedef float v4f __attribute__((ext_vector_type(4)));
typedef __attribute__((address_space(3))) uint32_t lds_u32;
typedef const __attribute__((address_space(1))) uint32_t glb_u32;

__device__ __forceinline__ void ins3(float v, int i,
                                     float& v0, float& v1, float& v2,
                                     int& i0, int& i1, int& i2) {
  // strict '>' keeps earlier (smaller-h) entries ahead on ties == lax.top_k
  if (v > v0)      { v2 = v1; i2 = i1; v1 = v0; i1 = i0; v0 = v; i0 = i; }
  else if (v > v1) { v2 = v1; i2 = i1; v1 = v;  i1 = i; }
  else if (v > v2) { v2 = v;  i2 = i; }
}

// K1: fused fp32 GEMM (nominee = integral_m @ mag[bc]) + running top-3 over h.
// B staged via global_load_lds, counted-vmcnt(4) double-buffer (r18-verified
// sync skeleton); A via uniform scalar loads. Merge scratch aliases the B
// double-buffer (fully dead after the kt loop; no cross-rowtile prefetch).
__global__ __launch_bounds__(256)
void hi_k1_gemm_top3(const float* __restrict__ mag,
                     const float* __restrict__ im,
                     float* __restrict__ wv, int* __restrict__ wi,
                     int nsplit) {
  const int tid  = threadIdx.x;
  const int lane = tid & 63;
  const int w    = tid >> 6;      // wave index 0..3
  const int t0 = blockIdx.x * BN;
  const int bc = blockIdx.y;
  const int sp = blockIdx.z;
  const int rt_begin = (sp * NRT) / nsplit;
  const int rt_end   = ((sp + 1) * NRT) / nsplit;

  __shared__ __align__(16) float Bs[2][BK * BN];   // [k][t] dbuf, 16KB each
  // merge scratch aliases Bs (entirely dead between the aliasing barriers)
  float* mv = (float*)&Bs[0][0];                   // 4*256*3 floats (12KB)
  int*   mi = (int*)(&Bs[0][0] + 4 * BN * KTOP);   // next 12KB

  const float* magbc = mag + (size_t)bc * F_DIM * T_DIM;

  // stage B rows k0..k0+15 into Bs[buf]: 4 x global_load_lds width=16 per
  // wave (wave-uniform LDS base, lane*16B; 1 row = exactly 1 wave-inst).
  auto stageB = [&](int buf, int k0) {
#pragma unroll
    for (int i = 0; i < 4; ++i) {
      int kr = w * 4 + i;
      const float* src = magbc + (size_t)(k0 + kr) * T_DIM + t0 + lane * 4;
      __builtin_amdgcn_global_load_lds(
          (glb_u32*)src, (lds_u32*)&Bs[buf][kr * BN], 16, 0, 0);
    }
  };

  float gv0 = -INFINITY, gv1 = -INFINITY, gv2 = -INFINITY;
  int   gi0 = 0, gi1 = 0, gi2 = 0;

  for (int rt = rt_begin; rt < rt_end; ++rt) {
    const int h0 = rt * BM;
    // wave-uniform row bases (SGPR): this wave's 8 rows, clamped (dup row
    // is masked at the top-3 stage exactly like r3-r18).
    int ab[8];
#pragma unroll
    for (int r = 0; r < 8; ++r) {
      int gh = h0 + w * 8 + r;
      if (gh >= H_DIM) gh = H_DIM - 1;
      ab[r] = __builtin_amdgcn_readfirstlane(gh * F_DIM);
    }

    float acc[8][4];
#pragma unroll
    for (int r = 0; r < 8; ++r)
#pragma unroll
      for (int c = 0; c < 4; ++c) acc[r][c] = 0.f;

    // prologue: 2 tiles in flight, wait tile 0 only (8 issued, vmcnt(4))
    stageB(0, 0);
    stageB(1, BK);
    asm volatile("s_waitcnt vmcnt(4)" ::: "memory");
    __builtin_amdgcn_s_barrier();
    __builtin_amdgcn_sched_barrier(0);

    int cur = 0;
    for (int kt = 0; kt < NKT; ++kt) {
      const int k0 = kt * BK;
      // compute: 4 groups of 4 k; A scalar (SGPR), B from LDS
#pragma unroll 2
      for (int g = 0; g < 4; ++g) {
        const int kk0 = k0 + g * 4;
        float a[8][4];
#pragma unroll
        for (int r = 0; r < 8; ++r)
#pragma unroll
          for (int q = 0; q < 4; ++q)
            a[r][q] = im[ab[r] + kk0 + q];    // uniform addr -> s_load
        v4f Bv[4];
#pragma unroll
        for (int q = 0; q < 4; ++q)
          Bv[q] = *(const v4f*)(&Bs[cur][(g * 4 + q) * BN + lane * 4]);
#pragma unroll
        for (int r = 0; r < 8; ++r)
#pragma unroll
          for (int q = 0; q < 4; ++q)
#pragma unroll
            for (int c = 0; c < 4; ++c)
              acc[r][c] = fmaf(a[r][q], Bv[q][c], acc[r][c]);
      }

      // barrier 1: all waves done reading Bs[cur]
      asm volatile("" ::: "memory");
      __builtin_amdgcn_s_barrier();
      __builtin_amdgcn_sched_barrier(0);

      if (kt + 2 < NKT) {
        stageB(cur, (kt + 2) * BK);
        // wait tile kt+1 landed (oldest; kt+2's 4 stay in flight)
        asm volatile("s_waitcnt vmcnt(4)" ::: "memory");
      } else {
        asm volatile("s_waitcnt vmcnt(0)" ::: "memory");
      }
      // barrier 2: every wave's slice of tile kt+1 is in LDS
      asm volatile("" ::: "memory");
      __builtin_amdgcn_s_barrier();
      __builtin_amdgcn_sched_barrier(0);
      cur ^= 1;
    }

    // K tail: k = 320 (single column), guarded scalar loads
    {
      float bt[4];
#pragma unroll
      for (int c = 0; c < 4; ++c) {
        int gt = t0 + lane * 4 + c;
        bt[c] = (gt < T_DIM) ? magbc[(size_t)(F_DIM - 1) * T_DIM + gt] : 0.f;
      }
#pragma unroll
      for (int r = 0; r < 8; ++r) {
        float av = im[ab[r] + (F_DIM - 1)];
#pragma unroll
        for (int c = 0; c < 4; ++c) acc[r][c] = fmaf(av, bt[c], acc[r][c]);
      }
    }

    // thread-local top-3 per column over own 8 rows (h ascending), store
    // per-wave lists in the (dead) Bs alias. Wave bands are h-ascending in
    // w, so the cross-wave merge below preserves lax.top_k tie order.
#pragma unroll
    for (int c = 0; c < 4; ++c) {
      const int col = lane * 4 + c;
      float v0 = -INFINITY, v1 = -INFINITY, v2 = -INFINITY;
      int   i0 = 0, i1 = 0, i2 = 0;
#pragma unroll
      for (int r = 0; r < 8; ++r) {
        int gh = h0 + w * 8 + r;
        float v = (gh < H_DIM) ? acc[r][c] : -INFINITY;
        ins3(v, gh, v0, v1, v2, i0, i1, i2);
      }
      mv[(w * BN + col) * 3 + 0] = v0;
      mv[(w * BN + col) * 3 + 1] = v1;
      mv[(w * BN + col) * 3 + 2] = v2;
      mi[(w * BN + col) * 3 + 0] = i0;
      mi[(w * BN + col) * 3 + 1] = i1;
      mi[(w * BN + col) * 3 + 2] = i2;
    }
    __syncthreads();
    // all 256 threads: thread tid owns column tid; merge 4 wave lists
    {
      const int col = tid;
#pragma unroll
      for (int ww = 0; ww < 4; ++ww)
#pragma unroll
        for (int j = 0; j < 3; ++j) {
          float v = mv[(ww * BN + col) * 3 + j];
          int   i = mi[(ww * BN + col) * 3 + j];
          ins3(v, i, gv0, gv1, gv2, gi0, gi1, gi2);
        }
    }
    __syncthreads();   // merge reads done before next rowtile stages Bs
  }

  {
    int t = t0 + tid;
    if (t < T_DIM) {
      size_t base = ((size_t)(bc * nsplit + sp) * KTOP) * T_DIM + t;
      wv[base]             = gv0;
      wv[base + T_DIM]     = gv1;
      wv[base + 2 * T_DIM] = gv2;
      wi[base]             = gi0;
      wi[base + T_DIM]     = gi1;
      wi[base + 2 * T_DIM] = gi2;
    }
  }
}

// K3: merge the nsplit partial top-3 lists, causal-pool the indices, gather
// harmonic_loc rows, sum over K, threshold, write (B,C,F,T) coalesced.
__global__ __launch_bounds__(256, 4)
void hi_k3_pool_gather(const float* __restrict__ wv, const int* __restrict__ wi,
                       const float* __restrict__ hl, float* __restrict__ out,
                       int nsplit) {
  const int tid = threadIdx.x;
  const int t0 = blockIdx.x * 64;
  const int bc = blockIdx.y;

  __shared__ float pos_lds[66 * KTOP];   // t0-2 .. t0+63
  __shared__ int   rows[64 * KTOP];
  __shared__ float S[64 * 65];           // [t_local][f_chunk] transpose buffer

  if (tid < 66) {
    int t = t0 - 2 + tid;
    float p0 = PADV, p1 = PADV, p2 = PADV;
    if (t >= 0 && t < T_DIM) {
      float v0 = -INFINITY, v1 = -INFINITY, v2 = -INFINITY;
      int i0 = 0, i1 = 0, i2 = 0;
      for (int sp = 0; sp < nsplit; ++sp)        // ascending h ranges
        for (int j = 0; j < KTOP; ++j) {         // descending values
          size_t idx = ((size_t)(bc * nsplit + sp) * KTOP + j) * T_DIM + t;
          ins3(wv[idx], wi[idx], v0, v1, v2, i0, i1, i2);
        }
      p0 = (float)i0; p1 = (float)i1; p2 = (float)i2;
    }
    pos_lds[tid * KTOP + 0] = p0;
    pos_lds[tid * KTOP + 1] = p1;
    pos_lds[tid * KTOP + 2] = p2;
  }
  __syncthreads();
  if (tid < 64) {
#pragma unroll
    for (int k = 0; k < KTOP; ++k) {
      float s = (pos_lds[tid * KTOP + k] + pos_lds[(tid + 1) * KTOP + k])
                + pos_lds[(tid + 2) * KTOP + k];
      rows[tid * KTOP + k] = (int)(s / 3.0f);   // matches ref fp32 /3 + int cast
    }
  }
  __syncthreads();

  const int w = tid >> 6, lane = tid & 63;
  for (int fc = 0; fc < 6; ++fc) {
    const int f0 = fc * 64;
    for (int i = 0; i < 16; ++i) {
      int tl = w * 16 + i;
      int r0 = rows[tl * KTOP + 0];
      int r1 = rows[tl * KTOP + 1];
      int r2 = rows[tl * KTOP + 2];
      int f = f0 + lane;
      float s = 0.f;
      if (f < F_DIM)
        s = (hl[(size_t)r0 * F_DIM + f] + hl[(size_t)r1 * F_DIM + f])
            + hl[(size_t)r2 * F_DIM + f];
      S[tl * 65 + lane] = s;
    }
    __syncthreads();
#pragma unroll
    for (int i = 0; i < 16; ++i) {
      int e = tid + 256 * i;
      int fl = e >> 6, tl = e & 63;
      int f = f0 + fl, t = t0 + tl;
      if (f < F_DIM && t < T_DIM)
        out[((size_t)bc * F_DIM + f) * T_DIM + t] = (S[tl * 65 + fl] > 0.f) ? 1.f : 0.f;
    }
    __syncthreads();
  }
}

extern "C" void kernel_launch(void* const* d_in, const int* in_sizes, int n_in,
                              void* d_out, int out_size, void* d_ws, size_t ws_size,
                              hipStream_t stream) {
  const float* mag = (const float*)d_in[0];   // (8,2,321,1000)
  const float* im  = (const float*)d_in[1];   // (4200,321)
  const float* hl  = (const float*)d_in[2];   // (4200,321)
  float* out = (float*)d_out;                 // (8,2,321,1000)

  // pick largest nsplit the workspace can hold (8 is known-safe: 3.07 MB)
  int nsplit = 8;
  if (ws_size >= (size_t)NBC * 32 * KTOP * T_DIM * 8) nsplit = 32;       // 12.3 MB
  else if (ws_size >= (size_t)NBC * 16 * KTOP * T_DIM * 8) nsplit = 16;  // 6.1 MB
  float* wv = (float*)d_ws;
  int*   wi = (int*)d_ws + (size_t)NBC * nsplit * KTOP * T_DIM;

  dim3 g1(NTT, NBC, nsplit);   // 4 x 16 x nsplit blocks
  hipLaunchKernelGGL(hi_k1_gemm_top3, g1, dim3(256), 0, stream, mag, im, wv, wi, nsplit);

  dim3 g3((T_DIM + 63) / 64, NBC);               // 16 x 16 = 256 blocks
  hipLaunchKernelGGL(hi_k3_pool_gather, g3, dim3(256), 0, stream, wv, wi, hl, out, nsplit);
}

// Round 20
// 938.127 us; speedup vs baseline: 4.6860x; 1.0237x over previous
//
#include <hip/hip_runtime.h>
#include <math.h>

// Problem constants
#define F_DIM 321
#define H_DIM 4200
#define T_DIM 1000
#define NBC   16      // B*C = 8*2
#define KTOP  3
#define PADV  1e-8f

// r20: ZERO-LDS, ZERO-BARRIER main loop. Eight r12-r19 variants (staging,
// sync, LDS size, occupancy, A-path) all plateaued at 960-1150us with
// VALUBusy pinned 31-40% == the m233 2-phase lockstep ceiling. The common
// skeleton was barrier-synced waves sharing an LDS tile. Now: wave owns
// 8 rows x 256 cols; A via uniform (SGPR) loads, B via named-register
// double-buffer straight from global (L1-hot: the block's 4 waves read the
// same 1KB lines); waves fully decoupled. LDS + barriers only in the
// once-per-rowtile top-3 merge.
#define BM 32         // h rows per block tile (4 waves x 8)
#define BN 256        // t cols per block tile (64 lanes x 4)
#define NRT 132       // ceil(H_DIM / BM)
#define NG  80        // 4-k groups covering k=0..319 (tail k=320 separate)
#define NTT 4         // ceil(T_DIM / BN)

typedef float v4f __attribute__((ext_vector_type(4)));

__device__ __forceinline__ void ins3(float v, int i,
                                     float& v0, float& v1, float& v2,
                                     int& i0, int& i1, int& i2) {
  // strict '>' keeps earlier (smaller-h) entries ahead on ties == lax.top_k
  if (v > v0)      { v2 = v1; i2 = i1; v1 = v0; i1 = i0; v0 = v; i0 = i; }
  else if (v > v1) { v2 = v1; i2 = i1; v1 = v;  i1 = i; }
  else if (v > v2) { v2 = v;  i2 = i; }
}

// load one 4-k B group (4 rows x 4 cols/lane) into 4 named v4f regs
#define LOADB(B0, B1, B2, B3, g) do {                                  \
    const float* _p = pB + (size_t)((g) * 4) * T_DIM;                  \
    B0 = *(const v4f*)(_p);                                            \
    B1 = *(const v4f*)(_p + T_DIM);                                    \
    B2 = *(const v4f*)(_p + 2 * T_DIM);                                \
    B3 = *(const v4f*)(_p + 3 * T_DIM);                                \
  } while (0)

// FMA one 4-k group: A uniform (SGPR operand), k-order q=0..3 ascending
#define FMAG(B0, B1, B2, B3, g) do {                                   \
    float _a[8][4];                                                    \
    _Pragma("unroll") for (int r = 0; r < 8; ++r)                      \
      _Pragma("unroll") for (int q = 0; q < 4; ++q)                    \
        _a[r][q] = im[ab[r] + (g) * 4 + q];                            \
    _Pragma("unroll") for (int r = 0; r < 8; ++r)                      \
      _Pragma("unroll") for (int c = 0; c < 4; ++c) {                  \
        acc[r][c] = fmaf(_a[r][0], B0[c], acc[r][c]);                  \
        acc[r][c] = fmaf(_a[r][1], B1[c], acc[r][c]);                  \
        acc[r][c] = fmaf(_a[r][2], B2[c], acc[r][c]);                  \
        acc[r][c] = fmaf(_a[r][3], B3[c], acc[r][c]);                  \
      }                                                                \
  } while (0)

// K1: fused fp32 GEMM (nominee = integral_m @ mag[bc]) + running top-3 over h.
__global__ __launch_bounds__(256)
void hi_k1_gemm_top3(const float* __restrict__ mag,
                     const float* __restrict__ im,
                     float* __restrict__ wv, int* __restrict__ wi,
                     int nsplit) {
  const int tid  = threadIdx.x;
  const int lane = tid & 63;
  const int w    = tid >> 6;      // wave index 0..3
  const int t0 = blockIdx.x * BN;
  const int bc = blockIdx.y;
  const int sp = blockIdx.z;
  const int rt_begin = (sp * NRT) / nsplit;
  const int rt_end   = ((sp + 1) * NRT) / nsplit;

  __shared__ float mv[4 * BN * KTOP];   // merge scratch only (12 KB)
  __shared__ int   mi[4 * BN * KTOP];   // (12 KB)

  const float* magbc = mag + (size_t)bc * F_DIM * T_DIM;
  const float* pB = magbc + t0 + lane * 4;   // per-lane B column base
  // (t overrun of the last t-tile reads into the next k-row: in-bounds for
  //  k<=319, and those columns are discarded at store time -- r19-verified)

  float gv0 = -INFINITY, gv1 = -INFINITY, gv2 = -INFINITY;
  int   gi0 = 0, gi1 = 0, gi2 = 0;

  for (int rt = rt_begin; rt < rt_end; ++rt) {
    const int h0 = rt * BM;
    // wave-uniform row bases (SGPR); clamp dups masked at top-3 (as r19)
    int ab[8];
#pragma unroll
    for (int r = 0; r < 8; ++r) {
      int gh = h0 + w * 8 + r;
      if (gh >= H_DIM) gh = H_DIM - 1;
      ab[r] = __builtin_amdgcn_readfirstlane(gh * F_DIM);
    }

    float acc[8][4];
#pragma unroll
    for (int r = 0; r < 8; ++r)
#pragma unroll
      for (int c = 0; c < 4; ++c) acc[r][c] = 0.f;

    v4f Bc0, Bc1, Bc2, Bc3, Bn0, Bn1, Bn2, Bn3;
    LOADB(Bc0, Bc1, Bc2, Bc3, 0);

    // 40 double-steps cover g=0..79 (k=0..319); prefetch 1 group ahead.
    // No LDS, no barriers: each wave free-runs; vmcnt waits are per-wave
    // and overlap the 256-cycle FMA block of the other buffer.
#pragma unroll 1
    for (int gs = 0; gs < NG / 2; ++gs) {
      const int ge = 2 * gs, go = 2 * gs + 1;
      LOADB(Bn0, Bn1, Bn2, Bn3, go);          // go <= 79 always
      FMAG(Bc0, Bc1, Bc2, Bc3, ge);
      if (ge + 2 < NG) LOADB(Bc0, Bc1, Bc2, Bc3, ge + 2);
      FMAG(Bn0, Bn1, Bn2, Bn3, go);
    }

    // K tail: k = 320 (single column), guarded loads
    {
      float bt[4];
#pragma unroll
      for (int c = 0; c < 4; ++c) {
        int gt = t0 + lane * 4 + c;
        bt[c] = (gt < T_DIM) ? magbc[(size_t)(F_DIM - 1) * T_DIM + gt] : 0.f;
      }
#pragma unroll
      for (int r = 0; r < 8; ++r) {
        float av = im[ab[r] + (F_DIM - 1)];
#pragma unroll
        for (int c = 0; c < 4; ++c) acc[r][c] = fmaf(av, bt[c], acc[r][c]);
      }
    }

    // thread-local top-3 per column over own 8 rows (h ascending); wave
    // bands ascend in w, so cross-wave merge preserves lax.top_k tie order.
#pragma unroll
    for (int c = 0; c < 4; ++c) {
      const int col = lane * 4 + c;
      float v0 = -INFINITY, v1 = -INFINITY, v2 = -INFINITY;
      int   i0 = 0, i1 = 0, i2 = 0;
#pragma unroll
      for (int r = 0; r < 8; ++r) {
        int gh = h0 + w * 8 + r;
        float v = (gh < H_DIM) ? acc[r][c] : -INFINITY;
        ins3(v, gh, v0, v1, v2, i0, i1, i2);
      }
      mv[(w * BN + col) * 3 + 0] = v0;
      mv[(w * BN + col) * 3 + 1] = v1;
      mv[(w * BN + col) * 3 + 2] = v2;
      mi[(w * BN + col) * 3 + 0] = i0;
      mi[(w * BN + col) * 3 + 1] = i1;
      mi[(w * BN + col) * 3 + 2] = i2;
    }
    __syncthreads();
    // thread tid owns column tid; merge the 4 wave lists (ascending h)
    {
      const int col = tid;
#pragma unroll
      for (int ww = 0; ww < 4; ++ww)
#pragma unroll
        for (int j = 0; j < 3; ++j) {
          float v = mv[(ww * BN + col) * 3 + j];
          int   i = mi[(ww * BN + col) * 3 + j];
          ins3(v, i, gv0, gv1, gv2, gi0, gi1, gi2);
        }
    }
    __syncthreads();   // merge reads done before next rowtile overwrites
  }

  {
    int t = t0 + tid;
    if (t < T_DIM) {
      size_t base = ((size_t)(bc * nsplit + sp) * KTOP) * T_DIM + t;
      wv[base]             = gv0;
      wv[base + T_DIM]     = gv1;
      wv[base + 2 * T_DIM] = gv2;
      wi[base]             = gi0;
      wi[base + T_DIM]     = gi1;
      wi[base + 2 * T_DIM] = gi2;
    }
  }
}

// K3: merge the nsplit partial top-3 lists, causal-pool the indices, gather
// harmonic_loc rows, sum over K, threshold, write (B,C,F,T) coalesced.
__global__ __launch_bounds__(256, 4)
void hi_k3_pool_gather(const float* __restrict__ wv, const int* __restrict__ wi,
                       const float* __restrict__ hl, float* __restrict__ out,
                       int nsplit) {
  const int tid = threadIdx.x;
  const int t0 = blockIdx.x * 64;
  const int bc = blockIdx.y;

  __shared__ float pos_lds[66 * KTOP];   // t0-2 .. t0+63
  __shared__ int   rows[64 * KTOP];
  __shared__ float S[64 * 65];           // [t_local][f_chunk] transpose buffer

  if (tid < 66) {
    int t = t0 - 2 + tid;
    float p0 = PADV, p1 = PADV, p2 = PADV;
    if (t >= 0 && t < T_DIM) {
      float v0 = -INFINITY, v1 = -INFINITY, v2 = -INFINITY;
      int i0 = 0, i1 = 0, i2 = 0;
      for (int sp = 0; sp < nsplit; ++sp)        // ascending h ranges
        for (int j = 0; j < KTOP; ++j) {         // descending values
          size_t idx = ((size_t)(bc * nsplit + sp) * KTOP + j) * T_DIM + t;
          ins3(wv[idx], wi[idx], v0, v1, v2, i0, i1, i2);
        }
      p0 = (float)i0; p1 = (float)i1; p2 = (float)i2;
    }
    pos_lds[tid * KTOP + 0] = p0;
    pos_lds[tid * KTOP + 1] = p1;
    pos_lds[tid * KTOP + 2] = p2;
  }
  __syncthreads();
  if (tid < 64) {
#pragma unroll
    for (int k = 0; k < KTOP; ++k) {
      float s = (pos_lds[tid * KTOP + k] + pos_lds[(tid + 1) * KTOP + k])
                + pos_lds[(tid + 2) * KTOP + k];
      rows[tid * KTOP + k] = (int)(s / 3.0f);   // matches ref fp32 /3 + int cast
    }
  }
  __syncthreads();

  const int w = tid >> 6, lane = tid & 63;
  for (int fc = 0; fc < 6; ++fc) {
    const int f0 = fc * 64;
    for (int i = 0; i < 16; ++i) {
      int tl = w * 16 + i;
      int r0 = rows[tl * KTOP + 0];
      int r1 = rows[tl * KTOP + 1];
      int r2 = rows[tl * KTOP + 2];
      int f = f0 + lane;
      float s = 0.f;
      if (f < F_DIM)
        s = (hl[(size_t)r0 * F_DIM + f] + hl[(size_t)r1 * F_DIM + f])
            + hl[(size_t)r2 * F_DIM + f];
      S[tl * 65 + lane] = s;
    }
    __syncthreads();
#pragma unroll
    for (int i = 0; i < 16; ++i) {
      int e = tid + 256 * i;
      int fl = e >> 6, tl = e & 63;
      int f = f0 + fl, t = t0 + tl;
      if (f < F_DIM && t < T_DIM)
        out[((size_t)bc * F_DIM + f) * T_DIM + t] = (S[tl * 65 + fl] > 0.f) ? 1.f : 0.f;
    }
    __syncthreads();
  }
}

extern "C" void kernel_launch(void* const* d_in, const int* in_sizes, int n_in,
                              void* d_out, int out_size, void* d_ws, size_t ws_size,
                              hipStream_t stream) {
  const float* mag = (const float*)d_in[0];   // (8,2,321,1000)
  const float* im  = (const float*)d_in[1];   // (4200,321)
  const float* hl  = (const float*)d_in[2];   // (4200,321)
  float* out = (float*)d_out;                 // (8,2,321,1000)

  // pick largest nsplit the workspace can hold (8 is known-safe: 3.07 MB)
  int nsplit = 8;
  if (ws_size >= (size_t)NBC * 32 * KTOP * T_DIM * 8) nsplit = 32;       // 12.3 MB
  else if (ws_size >= (size_t)NBC * 16 * KTOP * T_DIM * 8) nsplit = 16;  // 6.1 MB
  float* wv = (float*)d_ws;
  int*   wi = (int*)d_ws + (size_t)NBC * nsplit * KTOP * T_DIM;

  dim3 g1(NTT, NBC, nsplit);   // 4 x 16 x nsplit blocks
  hipLaunchKernelGGL(hi_k1_gemm_top3, g1, dim3(256), 0, stream, mag, im, wv, wi, nsplit);

  dim3 g3((T_DIM + 63) / 64, NBC);               // 16 x 16 = 256 blocks
  hipLaunchKernelGGL(hi_k3_pool_gather, g3, dim3(256), 0, stream, wv, wi, hl, out, nsplit);
}